// Round 3
// baseline (428.923 us; speedup 1.0000x reference)
//
#include <hip/hip_runtime.h>
#include <math.h>

// Problem constants (fixed by setup_inputs: B=32, H=480, W=640)
#define BB 32
#define HH 480
#define WW 640
#define HWN (HH * WW)
#define OH 34            // H // RESHAPE
#define OW 45            // W // RESHAPE
#define OHW (OH * OW)    // 1530
#define KTOP 153         // max(int(0.1*oh*ow), 10)
#define KS 25            // kernel size (odd)
#define PHW 12           // half kernel
#define PATCH (KS * KS)  // 625
#define RESHAPE_I 14
#define EPSV 1e-5f

// top-k machinery
#define TSLICE 10
#define TSW (OHW / TSLICE)   // 153 j's per slice

// global-median machinery: single 12-bit radix level (4096 bins), then
// 20 low bits resolved among collected candidates (~14k per (b,s)).
#define NB12 4096
#define PSLICE 32        // WGs per batch for histogram/error passes
#define NSLICE 16        // WGs per batch for collect pass (both signals/WG)
#define CAP 32768        // candidate cap per (b,s)  (expect ~14k)
#define LCAP 2048        // per-WG LDS candidate buffer per signal (expect ~900)
#define CPAD 32          // ccount stride in uints (128 B -> no false sharing)

#define EDGE_BLKS ((BB * OHW * 4) / 256)   // 765

// ---------- monotone float <-> uint key ----------
__device__ __forceinline__ unsigned int fkey(float f) {
  unsigned int u = __float_as_uint(f);
  return (u & 0x80000000u) ? ~u : (u | 0x80000000u);
}
__device__ __forceinline__ float fkey_inv(unsigned int k) {
  unsigned int u = (k & 0x80000000u) ? (k & 0x7FFFFFFFu) : ~k;
  return __uint_as_float(u);
}

// ---------- 256-thread block reduce (single) ----------
__device__ __forceinline__ float breduce256(float v, float* red) {
  const int t = threadIdx.x;
  __syncthreads();
  red[t] = v;
  __syncthreads();
  for (int s2 = 128; s2 > 0; s2 >>= 1) {
    if (t < s2) red[t] += red[t + s2];
    __syncthreads();
  }
  float r = red[0];
  __syncthreads();
  return r;
}

// ---------- 256-thread block reduce (pair) ----------
__device__ __forceinline__ float2 breduce256x2(float a, float b, float* red) {
  const int t = threadIdx.x;
  __syncthreads();
  red[t] = a;
  red[256 + t] = b;
  __syncthreads();
  for (int s2 = 128; s2 > 0; s2 >>= 1) {
    if (t < s2) {
      red[t] += red[t + s2];
      red[256 + t] += red[256 + t + s2];
    }
    __syncthreads();
  }
  float2 r = make_float2(red[0], red[256]);
  __syncthreads();
  return r;
}

// ---------- edge value at (b, y, x): sobel + erode(validity) + border mask ----------
__device__ float edge_at(const float* __restrict__ image, const unsigned char* __restrict__ vmask,
                         int b, int y, int x) {
  if (y < 3 || y >= HH - 3 || x < 3 || x >= WW - 3) return 0.f;
  const unsigned char* vm = vmask + (size_t)b * HWN;
  #pragma unroll
  for (int dy = -1; dy <= 1; ++dy) {
    #pragma unroll
    for (int dx = -1; dx <= 1; ++dx) {
      if (!vm[(size_t)(y + dy) * WW + (x + dx)]) return 0.f;
    }
  }
  const float* img = image + (size_t)b * 3 * HWN;
  float sx2 = 0.f, sy2 = 0.f;
  #pragma unroll
  for (int c = 0; c < 3; ++c) {
    const float* p = img + (size_t)c * HWN + (size_t)y * WW + x;
    float a00 = p[-WW - 1], a01 = p[-WW], a02 = p[-WW + 1];
    float a10 = p[-1],                    a12 = p[1];
    float a20 = p[WW - 1],  a21 = p[WW],  a22 = p[WW + 1];
    float gx = (-a00 + a02 + -2.f * a10 + 2.f * a12 + -a20 + a22) / 8.f;
    float gy = (-a00 + -2.f * a01 + -a02 + a20 + 2.f * a21 + a22) / 8.f;
    sx2 += gx * gx;
    sy2 += gy * gy;
  }
  float gxm = sqrtf(sx2 / 3.f);
  float gym = sqrtf(sy2 / 3.f);
  return sqrtf(gxm * gxm + gym * gym);
}

// ---------- K1: single-pass 12-bit histogram (key>>20), both signals ----------
__global__ __launch_bounds__(256) void gpass12_kernel(const float* __restrict__ inp,
                                                      const float* __restrict__ tgt,
                                                      const unsigned char* __restrict__ mask,
                                                      unsigned int* __restrict__ ghist) {
  const int b = blockIdx.x / PSLICE;
  const int sl = blockIdx.x % PSLICE;
  const int t = threadIdx.x;
  __shared__ unsigned int hist[2 * NB12];
  for (int i = t; i < 2 * NB12; i += 256) hist[i] = 0;
  __syncthreads();
  const float4* xi4 = (const float4*)(inp + (size_t)b * HWN);
  const float4* xt4 = (const float4*)(tgt + (size_t)b * HWN);
  const unsigned int* m4 = (const unsigned int*)(mask + (size_t)b * HWN);
  const int per4 = (HWN / PSLICE) / 4;  // 2400
  const int s0 = sl * per4;
  for (int i = s0 + t; i < s0 + per4; i += 256) {
    unsigned int mm = m4[i];
    if (!mm) continue;
    float4 a = xi4[i], c = xt4[i];
    if (mm & 0x000000FFu) { atomicAdd(&hist[fkey(a.x) >> 20], 1u); atomicAdd(&hist[NB12 + (fkey(c.x) >> 20)], 1u); }
    if (mm & 0x0000FF00u) { atomicAdd(&hist[fkey(a.y) >> 20], 1u); atomicAdd(&hist[NB12 + (fkey(c.y) >> 20)], 1u); }
    if (mm & 0x00FF0000u) { atomicAdd(&hist[fkey(a.z) >> 20], 1u); atomicAdd(&hist[NB12 + (fkey(c.z) >> 20)], 1u); }
    if (mm & 0xFF000000u) { atomicAdd(&hist[fkey(a.w) >> 20], 1u); atomicAdd(&hist[NB12 + (fkey(c.w) >> 20)], 1u); }
  }
  __syncthreads();
  for (int i = t; i < NB12; i += 256) {
    unsigned int h0 = hist[i], h1 = hist[NB12 + i];
    if (h0) atomicAdd(&ghist[(size_t)(b * 2 + 0) * NB12 + i], h0);
    if (h1) atomicAdd(&ghist[(size_t)(b * 2 + 1) * NB12 + i], h1);
  }
}

// ---------- K2: fused edge + bilinear resize, corner-parallel (no LDS) ----------
__global__ __launch_bounds__(256) void edge_resize_kernel(const float* __restrict__ image,
                                                          const unsigned char* __restrict__ vmask,
                                                          float* __restrict__ re) {
  int gid = blockIdx.x * 256 + threadIdx.x;
  int corner = gid & 3;
  int cell = gid >> 2;
  int b = cell / OHW;
  int rem = cell % OHW;
  int oy = rem / OW, ox = rem % OW;

  const float ry = (float)((double)HH / (double)OH);
  const float rx = (float)((double)WW / (double)OW);
  float cy = fminf(fmaxf(((float)oy + 0.5f) * ry - 0.5f, 0.f), (float)(HH - 1));
  float cx = fminf(fmaxf(((float)ox + 0.5f) * rx - 0.5f, 0.f), (float)(WW - 1));
  int y0 = (int)floorf(cy);
  int x0 = (int)floorf(cx);
  int y1 = min(y0 + 1, HH - 1);
  int x1 = min(x0 + 1, WW - 1);
  float wy = cy - (float)y0;
  float wx = cx - (float)x0;

  int yy = (corner & 2) ? y1 : y0;
  int xx = (corner & 1) ? x1 : x0;
  float w = ((corner & 2) ? wy : 1.f - wy) * ((corner & 1) ? wx : 1.f - wx);
  float g = edge_at(image, vmask, b, yy, xx) * w;
  g += __shfl_xor(g, 1, 64);
  g += __shfl_xor(g, 2, 64);
  if (corner == 0) re[cell] = g;
}

// ================= K3: topk_rank (blocks [0,320)) || gsel12 (blocks [320,384)) =================
__global__ __launch_bounds__(256) void k_rank_sel(const float* __restrict__ re,
                                                  const unsigned int* __restrict__ ghist,
                                                  int* __restrict__ rpart,
                                                  int* __restrict__ sel) {
  __shared__ float e[OHW];
  __shared__ unsigned int scan[256];
  const int t = threadIdx.x;
  if (blockIdx.x < BB * TSLICE) {
    // ---- partial ranks over j-slices ----
    const int b = blockIdx.x / TSLICE;
    const int sl = blockIdx.x % TSLICE;
    for (int i = t; i < OHW; i += 256) e[i] = re[b * OHW + i];
    __syncthreads();

    float vi[6];
    int idx[6], cnt[6];
    #pragma unroll
    for (int q = 0; q < 6; ++q) {
      int i = t + q * 256;
      idx[q] = i;
      vi[q] = (i < OHW) ? e[i] : 0.f;
      cnt[q] = 0;
    }
    const int j0 = sl * TSW;
    for (int jj = 0; jj < TSW; ++jj) {
      int j = j0 + jj;
      float u = e[j];  // broadcast
      #pragma unroll
      for (int q = 0; q < 6; ++q) {
        cnt[q] += (u > vi[q]) || (u == vi[q] && j < idx[q]);
      }
    }
    int* rp = rpart + ((size_t)b * TSLICE + sl) * OHW;
    #pragma unroll
    for (int q = 0; q < 6; ++q) {
      if (idx[q] < OHW) rp[idx[q]] = cnt[q];
    }
  } else {
    // ---- select median 12-bit bin per (b,s), parallel scan ----
    const int bs = blockIdx.x - BB * TSLICE;
    const unsigned int* gh = ghist + (size_t)bs * NB12;
    unsigned int local[16];
    unsigned int s = 0;
    const int base = t * 16;
    #pragma unroll
    for (int j = 0; j < 16; ++j) {
      local[j] = gh[base + j];
      s += local[j];
    }
    scan[t] = s;
    __syncthreads();
    for (int d = 1; d < 256; d <<= 1) {
      unsigned int v = (t >= d) ? scan[t - d] : 0u;
      __syncthreads();
      scan[t] += v;
      __syncthreads();
    }
    const unsigned int incl = scan[t];
    const unsigned int ex = incl - s;
    const unsigned int n = scan[255];
    if (n == 0) {
      if (t == 0) {
        sel[bs * 4 + 0] = -1;
        sel[bs * 4 + 1] = 0;
        sel[bs * 4 + 2] = 0;
        sel[bs * 4 + 3] = 0;
      }
      return;
    }
    const unsigned int r = (n - 1) >> 1;
    if (r >= ex && r < incl) {   // exactly one thread
      unsigned int cum = ex;
      int bin = base;
      #pragma unroll
      for (int j = 0; j < 16; ++j) {
        unsigned int h = local[j];
        if (cum + h > r) { bin = base + j; break; }
        cum += h;
      }
      sel[bs * 4 + 0] = bin;
      sel[bs * 4 + 1] = (int)(r - cum);
      sel[bs * 4 + 2] = (int)n;
      sel[bs * 4 + 3] = (int)cum;   // # elements strictly below bin
    }
  }
}

// ================= K4: gcollect both-signals (blocks [0,512)) || topk_write (blocks [512,544)) =================
__global__ __launch_bounds__(256) void k_collect_write(const float* __restrict__ inp,
                                                       const float* __restrict__ tgt,
                                                       const unsigned char* __restrict__ mask,
                                                       const int* __restrict__ sel,
                                                       const int* __restrict__ rpart,
                                                       float* __restrict__ cand,
                                                       unsigned int* __restrict__ ccount,
                                                       float* __restrict__ sbelow,
                                                       float* __restrict__ sabove,
                                                       int* __restrict__ coords) {
  __shared__ float bufi[LCAP];
  __shared__ float buft[LCAP];
  __shared__ float red[512];
  __shared__ unsigned int lcnti, lcntt, gbi, gbt;
  const int t = threadIdx.x;
  if (blockIdx.x < BB * NSLICE) {
    const int b = blockIdx.x / NSLICE;
    const int sl = blockIdx.x % NSLICE;
    const int pi = sel[(b * 2 + 0) * 4];
    const int pt = sel[(b * 2 + 1) * 4];
    if (t == 0) { lcnti = 0; lcntt = 0; }
    __syncthreads();
    float sbi = 0.f, sai = 0.f, sbt = 0.f, sat = 0.f;
    float* cdi = cand + (size_t)(b * 2 + 0) * CAP;
    float* cdt = cand + (size_t)(b * 2 + 1) * CAP;
    const float4* xi4 = (const float4*)(inp + (size_t)b * HWN);
    const float4* xt4 = (const float4*)(tgt + (size_t)b * HWN);
    const unsigned int* m4 = (const unsigned int*)(mask + (size_t)b * HWN);
    const int per4 = (HWN / NSLICE) / 4;   // 4800
    const int s0 = sl * per4;
    for (int i = s0 + t; i < s0 + per4; i += 256) {
      unsigned int mm = m4[i];
      if (!mm) continue;
      float4 a = xi4[i], c = xt4[i];
      // note: if pi/pt == -1 (n==0), every pf > prefix -> sums only, no appends
      #define GC2(av, cv, bit) \
        if (mm & bit) { \
          float v = av; \
          int pf = (int)(fkey(v) >> 20); \
          if (pf < pi) sbi += v; \
          else if (pf > pi) sai += v; \
          else { \
            unsigned int pos = atomicAdd(&lcnti, 1u); \
            if (pos < LCAP) bufi[pos] = v; \
            else { unsigned int g = atomicAdd(&ccount[(b * 2 + 0) * CPAD], 1u); if (g < CAP) cdi[g] = v; } \
          } \
          float w2 = cv; \
          int pg = (int)(fkey(w2) >> 20); \
          if (pg < pt) sbt += w2; \
          else if (pg > pt) sat += w2; \
          else { \
            unsigned int pos = atomicAdd(&lcntt, 1u); \
            if (pos < LCAP) buft[pos] = w2; \
            else { unsigned int g = atomicAdd(&ccount[(b * 2 + 1) * CPAD], 1u); if (g < CAP) cdt[g] = w2; } \
          } \
        }
      GC2(a.x, c.x, 0x000000FFu)
      GC2(a.y, c.y, 0x0000FF00u)
      GC2(a.z, c.z, 0x00FF0000u)
      GC2(a.w, c.w, 0xFF000000u)
      #undef GC2
    }
    __syncthreads();
    {
      unsigned int ci = min(lcnti, (unsigned int)LCAP);
      unsigned int ct = min(lcntt, (unsigned int)LCAP);
      if (t == 0) {
        if (ci > 0) gbi = atomicAdd(&ccount[(b * 2 + 0) * CPAD], ci);
        if (ct > 0) gbt = atomicAdd(&ccount[(b * 2 + 1) * CPAD], ct);
      }
      __syncthreads();
      for (unsigned int i = t; i < ci; i += 256) {
        unsigned int pos = gbi + i;
        if (pos < CAP) cdi[pos] = bufi[i];
      }
      for (unsigned int i = t; i < ct; i += 256) {
        unsigned int pos = gbt + i;
        if (pos < CAP) cdt[pos] = buft[i];
      }
    }
    float2 r1 = breduce256x2(sbi, sai, red);
    float2 r2 = breduce256x2(sbt, sat, red);
    if (t == 0) {
      atomicAdd(&sbelow[b * 2 + 0], r1.x);
      atomicAdd(&sabove[b * 2 + 0], r1.y);
      atomicAdd(&sbelow[b * 2 + 1], r2.x);
      atomicAdd(&sabove[b * 2 + 1], r2.y);
    }
  } else {
    // ---- sum partial ranks, scatter coords ----
    const int b = blockIdx.x - BB * NSLICE;
    const int* rp = rpart + (size_t)b * TSLICE * OHW;
    for (int i = t; i < OHW; i += 256) {
      int rank = 0;
      #pragma unroll
      for (int sl = 0; sl < TSLICE; ++sl) rank += rp[sl * OHW + i];
      if (rank < KTOP) {
        coords[(b * KTOP + rank) * 2 + 0] = (i / OW) * RESHAPE_I;
        coords[(b * KTOP + rank) * 2 + 1] = (i % OW) * RESHAPE_I;
      }
    }
  }
}

// ---------- K5: exact select among candidates (low 20 bits: 8/8/4) + scale ----------
__global__ __launch_bounds__(256) void gfinal_kernel(const float* __restrict__ cand,
                                                     const unsigned int* __restrict__ ccount,
                                                     const int* __restrict__ sel,
                                                     const float* __restrict__ sbelow,
                                                     const float* __restrict__ sabove,
                                                     float* __restrict__ gstats,
                                                     float* __restrict__ nvals) {
  const int bs = blockIdx.x;
  const int t = threadIdx.x;
  const int prefix = sel[bs * 4 + 0];
  const int r2 = sel[bs * 4 + 1];
  const int n = sel[bs * 4 + 2];
  const int nbelow = sel[bs * 4 + 3];
  __shared__ unsigned int hist[256];
  __shared__ float red[256];
  __shared__ int sh_bin, sh_r;
  __shared__ float sh_med;
  const float* cd = cand + (size_t)bs * CAP;
  int c = (int)min(ccount[bs * CPAD], (unsigned int)CAP);
  if (prefix < 0) {
    if (t == 0) {
      gstats[bs * 2 + 0] = 0.f;
      gstats[bs * 2 + 1] = 0.f;
      if ((bs & 1) == 0) nvals[bs >> 1] = 0.f;
    }
    return;
  }

  // pass 1: bits [19:12]
  hist[t] = 0;
  __syncthreads();
  for (int i = t; i < c; i += 256)
    atomicAdd(&hist[(fkey(cd[i]) >> 12) & 255u], 1u);
  __syncthreads();
  if (t == 0) {
    unsigned int rr = (unsigned int)r2, cum = 0;
    int bin = 0;
    for (; bin < 256; ++bin) {
      unsigned int h = hist[bin];
      if (cum + h > rr) break;
      cum += h;
    }
    sh_bin = bin;
    sh_r = (int)(rr - cum);
  }
  __syncthreads();
  const int bin1 = sh_bin;
  const int r3 = sh_r;

  // pass 2: bits [11:4]
  hist[t] = 0;
  __syncthreads();
  for (int i = t; i < c; i += 256) {
    unsigned int k = fkey(cd[i]);
    if (((k >> 12) & 255u) == (unsigned int)bin1)
      atomicAdd(&hist[(k >> 4) & 255u], 1u);
  }
  __syncthreads();
  if (t == 0) {
    unsigned int rr = (unsigned int)r3, cum = 0;
    int bin = 0;
    for (; bin < 256; ++bin) {
      unsigned int h = hist[bin];
      if (cum + h > rr) break;
      cum += h;
    }
    sh_bin = bin;
    sh_r = (int)(rr - cum);
  }
  __syncthreads();
  const int bin2 = sh_bin;
  const int r4 = sh_r;

  // pass 3: bits [3:0] (16 bins)
  if (t < 16) hist[t] = 0;
  __syncthreads();
  {
    const unsigned int want = (((unsigned int)bin1 << 8) | (unsigned int)bin2);
    for (int i = t; i < c; i += 256) {
      unsigned int k = fkey(cd[i]);
      if (((k >> 4) & 0xFFFFu) == want)
        atomicAdd(&hist[k & 15u], 1u);
    }
  }
  __syncthreads();
  if (t == 0) {
    unsigned int rr = (unsigned int)r4, cum = 0;
    int bin = 0;
    for (; bin < 16; ++bin) {
      unsigned int h = hist[bin];
      if (cum + h > rr) break;
      cum += h;
    }
    unsigned int key = ((unsigned int)prefix << 20) |
                       ((unsigned int)bin1 << 12) |
                       ((unsigned int)bin2 << 4) | (unsigned int)bin;
    sh_med = fkey_inv(key);
  }
  __syncthreads();
  const float med = sh_med;

  float ps = 0.f;
  for (int i = t; i < c; i += 256) ps += fabsf(cd[i] - med);
  float scand = breduce256(ps, red);
  if (t == 0) {
    float nb = (float)nbelow;
    float na = (float)(n - nbelow - c);
    float num = (nb * med - sbelow[bs]) + (sabove[bs] - na * med) + scand;
    gstats[bs * 2 + 0] = med;
    gstats[bs * 2 + 1] = num / fmaxf((float)n, 1.f);
    if ((bs & 1) == 0) nvals[bs >> 1] = (float)n;
  }
}

// ---------- K6: per-patch SSI error, single wave64 per patch (folds preduce) ----------
__global__ __launch_bounds__(64) void patch_kernel(const float* __restrict__ inp,
                                                   const float* __restrict__ tgt,
                                                   const unsigned char* __restrict__ mask,
                                                   const int* __restrict__ coords,
                                                   float* __restrict__ epnum,
                                                   float* __restrict__ epden) {
  const int bk = blockIdx.x;
  const int b = bk / KTOP;
  const int t = threadIdx.x;
  __shared__ unsigned int hist[512];   // [0:256) in, [256:512) tg
  __shared__ unsigned int sh_pref[2];
  __shared__ int sh_rank[2];

  const int cy = coords[bk * 2 + 0];
  const int cx = coords[bk * 2 + 1];

  float v_in[10], v_tg[10];
  unsigned int k_in[10], k_tg[10];
  unsigned int mbits = 0;
  #pragma unroll
  for (int q = 0; q < 10; ++q) {
    int i = t + q * 64;
    float vi = 0.f, vt = 0.f;
    if (i < PATCH) {
      int dy = i / KS - PHW, dx = i % KS - PHW;
      int y = cy + dy, x = cx + dx;
      if (y >= 0 && y < HH && x >= 0 && x < WW) {
        size_t off = (size_t)b * HWN + (size_t)y * WW + x;
        if (mask[off]) mbits |= (1u << q);
        vi = inp[off];
        vt = tgt[off];
      }
    }
    v_in[q] = vi; v_tg[q] = vt;
    k_in[q] = fkey(vi); k_tg[q] = fkey(vt);
  }

  // n = masked count (wave butterfly)
  int pn = __popc(mbits);
  #pragma unroll
  for (int d = 32; d > 0; d >>= 1) pn += __shfl_xor(pn, d, 64);
  const int n = pn;
  const float nf = (float)n;
  const int r = (n > 0) ? ((n - 1) >> 1) : 0;

  if (t == 0) {
    sh_pref[0] = 0; sh_pref[1] = 0;
    sh_rank[0] = r; sh_rank[1] = r;
  }
  __syncthreads();

  #pragma unroll
  for (int p = 0; p < 4; ++p) {
    const int shift = 24 - 8 * p;
    #pragma unroll
    for (int j = 0; j < 8; ++j) hist[t + 64 * j] = 0;
    __syncthreads();
    const int r_in = sh_rank[0], r_tg = sh_rank[1];
    const unsigned int pref_in = sh_pref[0], pref_tg = sh_pref[1];
    #pragma unroll
    for (int q = 0; q < 10; ++q) {
      if (mbits & (1u << q)) {
        unsigned int k = k_in[q];
        if (p == 0 || (k >> (shift + 8)) == pref_in)
          atomicAdd(&hist[(k >> shift) & 255u], 1u);
        unsigned int k2 = k_tg[q];
        if (p == 0 || (k2 >> (shift + 8)) == pref_tg)
          atomicAdd(&hist[256 + ((k2 >> shift) & 255u)], 1u);
      }
    }
    __syncthreads();
    // wave-scan descent, both signals: lane t owns bins 4t..4t+3
    {
      unsigned int a0 = hist[t * 4 + 0], a1 = hist[t * 4 + 1];
      unsigned int a2 = hist[t * 4 + 2], a3 = hist[t * 4 + 3];
      unsigned int b0 = hist[256 + t * 4 + 0], b1 = hist[256 + t * 4 + 1];
      unsigned int b2 = hist[256 + t * 4 + 2], b3 = hist[256 + t * 4 + 3];
      unsigned int sa0 = a0, sa1 = sa0 + a1, sa2 = sa1 + a2, sa3 = sa2 + a3;
      unsigned int sb0 = b0, sb1 = sb0 + b1, sb2 = sb1 + b2, sb3 = sb2 + b3;
      unsigned int ta = sa3, tb = sb3;
      #pragma unroll
      for (int d = 1; d < 64; d <<= 1) {
        unsigned int ua = (unsigned int)__shfl_up((int)ta, d, 64);
        unsigned int ub = (unsigned int)__shfl_up((int)tb, d, 64);
        if (t >= d) { ta += ua; tb += ub; }
      }
      unsigned int exa = ta - sa3, exb = tb - sb3;
      unsigned int rra = (unsigned int)r_in, rrb = (unsigned int)r_tg;
      unsigned int pa[4] = {exa, exa + sa0, exa + sa1, exa + sa2};
      unsigned int ca[4] = {exa + sa0, exa + sa1, exa + sa2, exa + sa3};
      unsigned int pb[4] = {exb, exb + sb0, exb + sb1, exb + sb2};
      unsigned int cb[4] = {exb + sb0, exb + sb1, exb + sb2, exb + sb3};
      #pragma unroll
      for (int j = 0; j < 4; ++j) {
        if (rra >= pa[j] && rra < ca[j]) {
          sh_pref[0] = (pref_in << 8) | (unsigned int)(t * 4 + j);
          sh_rank[0] = (int)(rra - pa[j]);
        }
        if (rrb >= pb[j] && rrb < cb[j]) {
          sh_pref[1] = (pref_tg << 8) | (unsigned int)(t * 4 + j);
          sh_rank[1] = (int)(rrb - pb[j]);
        }
      }
    }
    __syncthreads();
  }

  const float med_i = (n > 0) ? fkey_inv(sh_pref[0]) : 0.f;
  const float med_t = (n > 0) ? fkey_inv(sh_pref[1]) : 0.f;

  // masked mean abs deviation (wave butterflies)
  float pi = 0.f, pt = 0.f;
  #pragma unroll
  for (int q = 0; q < 10; ++q) {
    if (mbits & (1u << q)) {
      pi += fabsf(v_in[q] - med_i);
      pt += fabsf(v_tg[q] - med_t);
    }
  }
  #pragma unroll
  for (int d = 32; d > 0; d >>= 1) {
    pi += __shfl_xor(pi, d, 64);
    pt += __shfl_xor(pt, d, 64);
  }
  const float si = fmaxf(pi / fmaxf(nf, 1.f), EPSV);
  const float st = fmaxf(pt / fmaxf(nf, 1.f), EPSV);

  float pe = 0.f;
  #pragma unroll
  for (int q = 0; q < 10; ++q) {
    if (mbits & (1u << q)) {
      float a = (v_in[q] - med_i) / si;
      float c = (v_tg[q] - med_t) / st;
      pe += fmaxf(fabsf(a - c), EPSV);
    }
  }
  #pragma unroll
  for (int d = 32; d > 0; d >>= 1) pe += __shfl_xor(pe, d, 64);

  if (t == 0) {
    float valf = (n >= 4) ? 1.f : 0.f;
    float epv = sqrtf(fmaxf(pe / fmaxf(nf, 1.f), EPSV));
    atomicAdd(&epnum[b], epv * valf);
    atomicAdd(&epden[b], valf);
  }
}

// ================= K7: gerr + last-block finalize =================
__global__ __launch_bounds__(256) void k_gerr_final(const float* __restrict__ inp,
                                                    const float* __restrict__ tgt,
                                                    const unsigned char* __restrict__ mask,
                                                    const float* __restrict__ gstats,
                                                    const float* __restrict__ nvals,
                                                    const float* __restrict__ epnum,
                                                    const float* __restrict__ epden,
                                                    float* __restrict__ gacc,
                                                    unsigned int* __restrict__ gdone,
                                                    float* __restrict__ out) {
  const int b = blockIdx.x / PSLICE;
  const int sl = blockIdx.x % PSLICE;
  __shared__ float red[256];
  const int t = threadIdx.x;
  const float med_i = gstats[(b * 2 + 0) * 2 + 0];
  const float sc_i = fmaxf(gstats[(b * 2 + 0) * 2 + 1], EPSV);
  const float med_t = gstats[(b * 2 + 1) * 2 + 0];
  const float sc_t = fmaxf(gstats[(b * 2 + 1) * 2 + 1], EPSV);
  const float ri = 1.f / sc_i, rt = 1.f / sc_t;
  const float4* xi4 = (const float4*)(inp + (size_t)b * HWN);
  const float4* xt4 = (const float4*)(tgt + (size_t)b * HWN);
  const unsigned int* m4 = (const unsigned int*)(mask + (size_t)b * HWN);
  const int per4 = (HWN / PSLICE) / 4;
  const int s0 = sl * per4;
  float part = 0.f;
  for (int i = s0 + t; i < s0 + per4; i += 256) {
    unsigned int mm = m4[i];
    if (!mm) continue;
    float4 a = xi4[i], c = xt4[i];
    if (mm & 0x000000FFu) part += fmaxf(fabsf((a.x - med_i) * ri - (c.x - med_t) * rt), EPSV);
    if (mm & 0x0000FF00u) part += fmaxf(fabsf((a.y - med_i) * ri - (c.y - med_t) * rt), EPSV);
    if (mm & 0x00FF0000u) part += fmaxf(fabsf((a.z - med_i) * ri - (c.z - med_t) * rt), EPSV);
    if (mm & 0xFF000000u) part += fmaxf(fabsf((a.w - med_i) * ri - (c.w - med_t) * rt), EPSV);
  }
  float tp = breduce256(part, red);
  if (t == 0) {
    atomicAdd(&gacc[b], tp);
    __threadfence();                           // release our partial before signaling
    unsigned int prev = atomicAdd(&gdone[b], 1u);
    if (prev == PSLICE - 1) {                  // last block for this batch
      __threadfence();                         // acquire all partials
      float g = atomicAdd(&gacc[b], 0.0f);     // atomic read (L2-coherent)
      float n = nvals[b];
      float epb = epnum[b] / fmaxf(epden[b], 1.f);
      float eg = sqrtf(fmaxf(g / fmaxf(n, 1.f), EPSV));
      out[b] = 0.5f * (epb + eg);
    }
  }
}

extern "C" void kernel_launch(void* const* d_in, const int* in_sizes, int n_in,
                              void* d_out, int out_size, void* d_ws, size_t ws_size,
                              hipStream_t stream) {
  const float* inp = (const float*)d_in[0];
  const float* tgt = (const float*)d_in[1];
  const unsigned char* mask = (const unsigned char*)d_in[2];   // jax bool -> 1 byte
  const float* image = (const float*)d_in[3];
  const unsigned char* vmask = (const unsigned char*)d_in[4];  // jax bool -> 1 byte
  float* out = (float*)d_out;

  float* ws = (float*)d_ws;
  float* re = ws;                                    // 48960 floats
  int* coords = (int*)(ws + 48960);                  // 9792 ints
  float* gstats = (float*)(coords + 9792);           // 128
  float* nvals = gstats + 128;                       // 32
  int* sel = (int*)(nvals + 32);                     // 256 ints
  int* rpart = sel + 256;                            // BB*TSLICE*OHW = 489600 ints
  float* cand = (float*)(rpart + 489600);            // 64*CAP floats
  // zeroed region (one contiguous memset)
  unsigned int* ghist = (unsigned int*)(cand + (size_t)64 * CAP);  // 64*NB12
  unsigned int* ccount = ghist + (size_t)64 * NB12;                // 64*CPAD
  float* sbelow = (float*)(ccount + 64 * CPAD);                    // 64
  float* sabove = sbelow + 64;                                     // 64
  float* gacc = sabove + 64;                                       // 32
  unsigned int* gdone = (unsigned int*)(gacc + 32);                // 32
  float* epnum = (float*)(gdone + 32);                             // 32
  float* epden = epnum + 32;                                       // 32
  size_t zero_bytes = ((size_t)64 * NB12 + 64 * CPAD + 64 + 64 + 32 + 32 + 32 + 32) * 4;
  hipMemsetAsync(ghist, 0, zero_bytes, stream);

  gpass12_kernel<<<BB * PSLICE, 256, 0, stream>>>(inp, tgt, mask, ghist);
  edge_resize_kernel<<<EDGE_BLKS, 256, 0, stream>>>(image, vmask, re);
  k_rank_sel<<<BB * TSLICE + 64, 256, 0, stream>>>(re, ghist, rpart, sel);
  k_collect_write<<<BB * NSLICE + BB, 256, 0, stream>>>(inp, tgt, mask, sel, rpart, cand, ccount,
                                                        sbelow, sabove, coords);
  gfinal_kernel<<<BB * 2, 256, 0, stream>>>(cand, ccount, sel, sbelow, sabove, gstats, nvals);
  patch_kernel<<<BB * KTOP, 64, 0, stream>>>(inp, tgt, mask, coords, epnum, epden);
  k_gerr_final<<<BB * PSLICE, 256, 0, stream>>>(inp, tgt, mask, gstats, nvals, epnum, epden,
                                                gacc, gdone, out);
}

// Round 4
// 393.225 us; speedup vs baseline: 1.0908x; 1.0908x over previous
//
#include <hip/hip_runtime.h>
#include <math.h>

// Problem constants (fixed by setup_inputs: B=32, H=480, W=640)
#define BB 32
#define HH 480
#define WW 640
#define HWN (HH * WW)
#define OH 34            // H // RESHAPE
#define OW 45            // W // RESHAPE
#define OHW (OH * OW)    // 1530
#define KTOP 153         // max(int(0.1*oh*ow), 10)
#define KS 25            // kernel size (odd)
#define PHW 12           // half kernel
#define PATCH (KS * KS)  // 625
#define RESHAPE_I 14
#define EPSV 1e-5f

// top-k machinery
#define TSLICE 10
#define TSW (OHW / TSLICE)   // 153 j's per slice

// global-median machinery: single 12-bit radix level (4096 bins), then
// 20 low bits resolved among collected candidates (~14k per (b,s)).
#define NB12 4096
#define PSLICE 32        // WGs per batch for histogram/error passes
#define NSLICE 16        // WGs per (b,s) for collect pass
#define CAP 32768        // candidate cap per (b,s)  (expect ~14k)
#define LCAP 2048        // per-WG LDS candidate buffer (expect ~900 used)
#define CPAD 32          // ccount stride in uints (128 B -> no false sharing)

// ---------- monotone float <-> uint key ----------
__device__ __forceinline__ unsigned int fkey(float f) {
  unsigned int u = __float_as_uint(f);
  return (u & 0x80000000u) ? ~u : (u | 0x80000000u);
}
__device__ __forceinline__ float fkey_inv(unsigned int k) {
  unsigned int u = (k & 0x80000000u) ? (k & 0x7FFFFFFFu) : ~k;
  return __uint_as_float(u);
}

// ---------- 256-thread block reduce (single) ----------
__device__ __forceinline__ float breduce256(float v, float* red) {
  const int t = threadIdx.x;
  __syncthreads();
  red[t] = v;
  __syncthreads();
  for (int s2 = 128; s2 > 0; s2 >>= 1) {
    if (t < s2) red[t] += red[t + s2];
    __syncthreads();
  }
  float r = red[0];
  __syncthreads();
  return r;
}

// ---------- 256-thread block reduce (pair) ----------
__device__ __forceinline__ float2 breduce256x2(float a, float b, float* red) {
  const int t = threadIdx.x;
  __syncthreads();
  red[t] = a;
  red[256 + t] = b;
  __syncthreads();
  for (int s2 = 128; s2 > 0; s2 >>= 1) {
    if (t < s2) {
      red[t] += red[t + s2];
      red[256 + t] += red[256 + t + s2];
    }
    __syncthreads();
  }
  float2 r = make_float2(red[0], red[256]);
  __syncthreads();
  return r;
}

// ---------- edge value at (b, y, x): sobel + erode(validity) + border mask ----------
__device__ float edge_at(const float* __restrict__ image, const unsigned char* __restrict__ vmask,
                         int b, int y, int x) {
  if (y < 3 || y >= HH - 3 || x < 3 || x >= WW - 3) return 0.f;
  const unsigned char* vm = vmask + (size_t)b * HWN;
  #pragma unroll
  for (int dy = -1; dy <= 1; ++dy) {
    #pragma unroll
    for (int dx = -1; dx <= 1; ++dx) {
      if (!vm[(size_t)(y + dy) * WW + (x + dx)]) return 0.f;
    }
  }
  const float* img = image + (size_t)b * 3 * HWN;
  float sx2 = 0.f, sy2 = 0.f;
  #pragma unroll
  for (int c = 0; c < 3; ++c) {
    const float* p = img + (size_t)c * HWN + (size_t)y * WW + x;
    float a00 = p[-WW - 1], a01 = p[-WW], a02 = p[-WW + 1];
    float a10 = p[-1],                    a12 = p[1];
    float a20 = p[WW - 1],  a21 = p[WW],  a22 = p[WW + 1];
    float gx = (-a00 + a02 + -2.f * a10 + 2.f * a12 + -a20 + a22) / 8.f;
    float gy = (-a00 + -2.f * a01 + -a02 + a20 + 2.f * a21 + a22) / 8.f;
    sx2 += gx * gx;
    sy2 += gy * gy;
  }
  float gxm = sqrtf(sx2 / 3.f);
  float gym = sqrtf(sy2 / 3.f);
  return sqrtf(gxm * gxm + gym * gym);
}

// ---------- K1: fused edge + bilinear resize, corner-parallel ----------
__global__ __launch_bounds__(256) void edge_resize_kernel(const float* __restrict__ image,
                                                          const unsigned char* __restrict__ vmask,
                                                          float* __restrict__ re) {
  int gid = blockIdx.x * 256 + threadIdx.x;
  int corner = gid & 3;
  int cell = gid >> 2;
  int b = cell / OHW;
  int rem = cell % OHW;
  int oy = rem / OW, ox = rem % OW;

  const float ry = (float)((double)HH / (double)OH);
  const float rx = (float)((double)WW / (double)OW);
  float cy = fminf(fmaxf(((float)oy + 0.5f) * ry - 0.5f, 0.f), (float)(HH - 1));
  float cx = fminf(fmaxf(((float)ox + 0.5f) * rx - 0.5f, 0.f), (float)(WW - 1));
  int y0 = (int)floorf(cy);
  int x0 = (int)floorf(cx);
  int y1 = min(y0 + 1, HH - 1);
  int x1 = min(x0 + 1, WW - 1);
  float wy = cy - (float)y0;
  float wx = cx - (float)x0;

  int yy = (corner & 2) ? y1 : y0;
  int xx = (corner & 1) ? x1 : x0;
  float w = ((corner & 2) ? wy : 1.f - wy) * ((corner & 1) ? wx : 1.f - wx);
  float g = edge_at(image, vmask, b, yy, xx) * w;
  g += __shfl_xor(g, 1, 64);
  g += __shfl_xor(g, 2, 64);
  if (corner == 0) re[cell] = g;
}

// ---------- K2a: partial ranks over j-slices ----------
__global__ __launch_bounds__(256) void topk_rank_kernel(const float* __restrict__ re,
                                                        int* __restrict__ rpart) {
  const int b = blockIdx.x / TSLICE;
  const int sl = blockIdx.x % TSLICE;
  const int t = threadIdx.x;
  __shared__ float e[OHW];
  for (int i = t; i < OHW; i += 256) e[i] = re[b * OHW + i];
  __syncthreads();

  float vi[6];
  int idx[6], cnt[6];
  #pragma unroll
  for (int q = 0; q < 6; ++q) {
    int i = t + q * 256;
    idx[q] = i;
    vi[q] = (i < OHW) ? e[i] : 0.f;
    cnt[q] = 0;
  }
  const int j0 = sl * TSW;
  for (int jj = 0; jj < TSW; ++jj) {
    int j = j0 + jj;
    float u = e[j];  // broadcast
    #pragma unroll
    for (int q = 0; q < 6; ++q) {
      cnt[q] += (u > vi[q]) || (u == vi[q] && j < idx[q]);
    }
  }
  int* rp = rpart + ((size_t)b * TSLICE + sl) * OHW;
  #pragma unroll
  for (int q = 0; q < 6; ++q) {
    if (idx[q] < OHW) rp[idx[q]] = cnt[q];
  }
}

// ---------- K2b: sum partial ranks, scatter coords ----------
__global__ __launch_bounds__(256) void topk_write_kernel(const int* __restrict__ rpart,
                                                         int* __restrict__ coords) {
  const int b = blockIdx.x;
  const int t = threadIdx.x;
  const int* rp = rpart + (size_t)b * TSLICE * OHW;
  for (int i = t; i < OHW; i += 256) {
    int rank = 0;
    #pragma unroll
    for (int sl = 0; sl < TSLICE; ++sl) rank += rp[sl * OHW + i];
    if (rank < KTOP) {
      coords[(b * KTOP + rank) * 2 + 0] = (i / OW) * RESHAPE_I;
      coords[(b * KTOP + rank) * 2 + 1] = (i % OW) * RESHAPE_I;
    }
  }
}

// ---------- K3: per-patch SSI error, single wave64 per patch ----------
// 10 elems/lane in registers; 4-pass 8-bit radix select with wave-shfl scan.
// __launch_bounds__(64,4): cap 128 VGPRs so the 20-float element arrays stay
// in registers (default allocation spilled them to scratch -> all-pipes-idle).
// Keys are recomputed from values (fkey = 2 VALU ops) instead of stored.
__global__ __launch_bounds__(64, 4) void patch_kernel(const float* __restrict__ inp,
                                                      const float* __restrict__ tgt,
                                                      const unsigned char* __restrict__ mask,
                                                      const int* __restrict__ coords,
                                                      float* __restrict__ ep, float* __restrict__ val) {
  const int bk = blockIdx.x;
  const int b = bk / KTOP;
  const int t = threadIdx.x;
  __shared__ unsigned int hist[512];   // [0:256) in, [256:512) tg
  __shared__ unsigned int sh_pref[2];
  __shared__ int sh_rank[2];

  const int cy = coords[bk * 2 + 0];
  const int cx = coords[bk * 2 + 1];

  float v_in[10], v_tg[10];
  unsigned int mbits = 0;
  #pragma unroll
  for (int q = 0; q < 10; ++q) {
    int i = t + q * 64;
    float vi = 0.f, vt = 0.f;
    if (i < PATCH) {
      int dy = i / KS - PHW, dx = i % KS - PHW;
      int y = cy + dy, x = cx + dx;
      if (y >= 0 && y < HH && x >= 0 && x < WW) {
        size_t off = (size_t)b * HWN + (size_t)y * WW + x;
        if (mask[off]) mbits |= (1u << q);
        vi = inp[off];
        vt = tgt[off];
      }
    }
    v_in[q] = vi; v_tg[q] = vt;
  }

  // n = masked count (wave butterfly)
  int pn = __popc(mbits);
  #pragma unroll
  for (int d = 32; d > 0; d >>= 1) pn += __shfl_xor(pn, d, 64);
  const int n = pn;
  const float nf = (float)n;
  const int r = (n > 0) ? ((n - 1) >> 1) : 0;

  if (t == 0) {
    sh_pref[0] = 0; sh_pref[1] = 0;
    sh_rank[0] = r; sh_rank[1] = r;
  }
  __syncthreads();

  #pragma unroll
  for (int p = 0; p < 4; ++p) {
    const int shift = 24 - 8 * p;
    #pragma unroll
    for (int j = 0; j < 8; ++j) hist[t + 64 * j] = 0;
    __syncthreads();
    const int r_in = sh_rank[0], r_tg = sh_rank[1];
    const unsigned int pref_in = sh_pref[0], pref_tg = sh_pref[1];
    #pragma unroll
    for (int q = 0; q < 10; ++q) {
      if (mbits & (1u << q)) {
        unsigned int k = fkey(v_in[q]);
        if (p == 0 || (k >> (shift + 8)) == pref_in)
          atomicAdd(&hist[(k >> shift) & 255u], 1u);
        unsigned int k2 = fkey(v_tg[q]);
        if (p == 0 || (k2 >> (shift + 8)) == pref_tg)
          atomicAdd(&hist[256 + ((k2 >> shift) & 255u)], 1u);
      }
    }
    __syncthreads();
    // wave-scan descent, both signals: lane t owns bins 4t..4t+3
    {
      unsigned int a0 = hist[t * 4 + 0], a1 = hist[t * 4 + 1];
      unsigned int a2 = hist[t * 4 + 2], a3 = hist[t * 4 + 3];
      unsigned int b0 = hist[256 + t * 4 + 0], b1 = hist[256 + t * 4 + 1];
      unsigned int b2 = hist[256 + t * 4 + 2], b3 = hist[256 + t * 4 + 3];
      unsigned int sa0 = a0, sa1 = sa0 + a1, sa2 = sa1 + a2, sa3 = sa2 + a3;
      unsigned int sb0 = b0, sb1 = sb0 + b1, sb2 = sb1 + b2, sb3 = sb2 + b3;
      unsigned int ta = sa3, tb = sb3;
      #pragma unroll
      for (int d = 1; d < 64; d <<= 1) {
        unsigned int ua = (unsigned int)__shfl_up((int)ta, d, 64);
        unsigned int ub = (unsigned int)__shfl_up((int)tb, d, 64);
        if (t >= d) { ta += ua; tb += ub; }
      }
      unsigned int exa = ta - sa3, exb = tb - sb3;
      unsigned int rra = (unsigned int)r_in, rrb = (unsigned int)r_tg;
      unsigned int pa[4] = {exa, exa + sa0, exa + sa1, exa + sa2};
      unsigned int ca[4] = {exa + sa0, exa + sa1, exa + sa2, exa + sa3};
      unsigned int pb[4] = {exb, exb + sb0, exb + sb1, exb + sb2};
      unsigned int cb[4] = {exb + sb0, exb + sb1, exb + sb2, exb + sb3};
      #pragma unroll
      for (int j = 0; j < 4; ++j) {
        if (rra >= pa[j] && rra < ca[j]) {
          sh_pref[0] = (pref_in << 8) | (unsigned int)(t * 4 + j);
          sh_rank[0] = (int)(rra - pa[j]);
        }
        if (rrb >= pb[j] && rrb < cb[j]) {
          sh_pref[1] = (pref_tg << 8) | (unsigned int)(t * 4 + j);
          sh_rank[1] = (int)(rrb - pb[j]);
        }
      }
    }
    __syncthreads();
  }

  const float med_i = (n > 0) ? fkey_inv(sh_pref[0]) : 0.f;
  const float med_t = (n > 0) ? fkey_inv(sh_pref[1]) : 0.f;

  // masked mean abs deviation (wave butterflies)
  float pi = 0.f, pt = 0.f;
  #pragma unroll
  for (int q = 0; q < 10; ++q) {
    if (mbits & (1u << q)) {
      pi += fabsf(v_in[q] - med_i);
      pt += fabsf(v_tg[q] - med_t);
    }
  }
  #pragma unroll
  for (int d = 32; d > 0; d >>= 1) {
    pi += __shfl_xor(pi, d, 64);
    pt += __shfl_xor(pt, d, 64);
  }
  const float si = fmaxf(pi / fmaxf(nf, 1.f), EPSV);
  const float st = fmaxf(pt / fmaxf(nf, 1.f), EPSV);

  float pe = 0.f;
  #pragma unroll
  for (int q = 0; q < 10; ++q) {
    if (mbits & (1u << q)) {
      float a = (v_in[q] - med_i) / si;
      float c = (v_tg[q] - med_t) / st;
      pe += fmaxf(fabsf(a - c), EPSV);
    }
  }
  #pragma unroll
  for (int d = 32; d > 0; d >>= 1) pe += __shfl_xor(pe, d, 64);

  if (t == 0) {
    ep[bk] = sqrtf(fmaxf(pe / fmaxf(nf, 1.f), EPSV));
    val[bk] = (n >= 4) ? 1.f : 0.f;
  }
}

// ---------- K4: e_patch[b] ----------
__global__ __launch_bounds__(256) void preduce_kernel(const float* __restrict__ ep,
                                                      const float* __restrict__ val,
                                                      float* __restrict__ e_patch) {
  const int b = blockIdx.x;
  const int t = threadIdx.x;
  __shared__ float red[512];
  float se = 0.f, sv = 0.f;
  for (int i = t; i < KTOP; i += 256) {
    float v = val[b * KTOP + i];
    se += ep[b * KTOP + i] * v;
    sv += v;
  }
  float2 tt = breduce256x2(se, sv, red);
  if (t == 0) e_patch[b] = tt.x / fmaxf(tt.y, 1.f);
}

// ---------- K5a: single-pass 12-bit histogram (key>>20), both signals ----------
__global__ __launch_bounds__(256) void gpass12_kernel(const float* __restrict__ inp,
                                                      const float* __restrict__ tgt,
                                                      const unsigned char* __restrict__ mask,
                                                      unsigned int* __restrict__ ghist) {
  const int b = blockIdx.x / PSLICE;
  const int sl = blockIdx.x % PSLICE;
  const int t = threadIdx.x;
  __shared__ unsigned int hist[2 * NB12];
  for (int i = t; i < 2 * NB12; i += 256) hist[i] = 0;
  __syncthreads();
  const float4* xi4 = (const float4*)(inp + (size_t)b * HWN);
  const float4* xt4 = (const float4*)(tgt + (size_t)b * HWN);
  const unsigned int* m4 = (const unsigned int*)(mask + (size_t)b * HWN);
  const int per4 = (HWN / PSLICE) / 4;  // 2400
  const int s0 = sl * per4;
  for (int i = s0 + t; i < s0 + per4; i += 256) {
    unsigned int mm = m4[i];
    if (!mm) continue;
    float4 a = xi4[i], c = xt4[i];
    if (mm & 0x000000FFu) { atomicAdd(&hist[fkey(a.x) >> 20], 1u); atomicAdd(&hist[NB12 + (fkey(c.x) >> 20)], 1u); }
    if (mm & 0x0000FF00u) { atomicAdd(&hist[fkey(a.y) >> 20], 1u); atomicAdd(&hist[NB12 + (fkey(c.y) >> 20)], 1u); }
    if (mm & 0x00FF0000u) { atomicAdd(&hist[fkey(a.z) >> 20], 1u); atomicAdd(&hist[NB12 + (fkey(c.z) >> 20)], 1u); }
    if (mm & 0xFF000000u) { atomicAdd(&hist[fkey(a.w) >> 20], 1u); atomicAdd(&hist[NB12 + (fkey(c.w) >> 20)], 1u); }
  }
  __syncthreads();
  for (int i = t; i < NB12; i += 256) {
    unsigned int h0 = hist[i], h1 = hist[NB12 + i];
    if (h0) atomicAdd(&ghist[(size_t)(b * 2 + 0) * NB12 + i], h0);
    if (h1) atomicAdd(&ghist[(size_t)(b * 2 + 1) * NB12 + i], h1);
  }
}

// ---------- K5b: select median 12-bit bin per (b,s), parallel scan ----------
__global__ __launch_bounds__(256) void gsel12_kernel(const unsigned int* __restrict__ ghist,
                                                     int* __restrict__ sel) {
  const int bs = blockIdx.x;
  const int t = threadIdx.x;
  const unsigned int* gh = ghist + (size_t)bs * NB12;
  __shared__ unsigned int scan[256];
  unsigned int local[16];
  unsigned int s = 0;
  const int base = t * 16;
  #pragma unroll
  for (int j = 0; j < 16; ++j) {
    local[j] = gh[base + j];
    s += local[j];
  }
  scan[t] = s;
  __syncthreads();
  for (int d = 1; d < 256; d <<= 1) {
    unsigned int v = (t >= d) ? scan[t - d] : 0u;
    __syncthreads();
    scan[t] += v;
    __syncthreads();
  }
  const unsigned int incl = scan[t];
  const unsigned int ex = incl - s;
  const unsigned int n = scan[255];
  if (n == 0) {
    if (t == 0) {
      sel[bs * 4 + 0] = -1;
      sel[bs * 4 + 1] = 0;
      sel[bs * 4 + 2] = 0;
      sel[bs * 4 + 3] = 0;
    }
    return;
  }
  const unsigned int r = (n - 1) >> 1;
  if (r >= ex && r < incl) {   // exactly one thread
    unsigned int cum = ex;
    int bin = base;
    #pragma unroll
    for (int j = 0; j < 16; ++j) {
      unsigned int h = local[j];
      if (cum + h > r) { bin = base + j; break; }
      cum += h;
    }
    sel[bs * 4 + 0] = bin;
    sel[bs * 4 + 1] = (int)(r - cum);
    sel[bs * 4 + 2] = (int)n;
    sel[bs * 4 + 3] = (int)cum;   // # elements strictly below bin
  }
}

// ---------- K5c: collect median-bin candidates + below/above sums ----------
__global__ __launch_bounds__(256) void gcollect_kernel(const float* __restrict__ inp,
                                                       const float* __restrict__ tgt,
                                                       const unsigned char* __restrict__ mask,
                                                       const int* __restrict__ sel,
                                                       float* __restrict__ cand,
                                                       unsigned int* __restrict__ ccount,
                                                       float* __restrict__ sbelow,
                                                       float* __restrict__ sabove) {
  const int bs = blockIdx.x / NSLICE;
  const int sl = blockIdx.x % NSLICE;
  const int b = bs >> 1, s = bs & 1;
  const float* x = (s == 0 ? inp : tgt) + (size_t)b * HWN;
  const unsigned char* m = mask + (size_t)b * HWN;
  const int prefix = sel[bs * 4 + 0];
  __shared__ float red[512];
  __shared__ float buf[LCAP];
  __shared__ unsigned int lcnt, gbase;
  const int t = threadIdx.x;
  if (t == 0) lcnt = 0;
  __syncthreads();
  float sb = 0.f, sa = 0.f;
  if (prefix >= 0) {
    float* cd = cand + (size_t)bs * CAP;
    const float4* x4 = (const float4*)x;
    const unsigned int* m4 = (const unsigned int*)m;
    const int per4 = (HWN / NSLICE) / 4;
    const int s0 = sl * per4;
    for (int i = s0 + t; i < s0 + per4; i += 256) {
      unsigned int mm = m4[i];
      if (!mm) continue;
      float4 a = x4[i];
      #define GCOL(av, bit) \
        if (mm & bit) { \
          float v = av; \
          int pf = (int)(fkey(v) >> 20); \
          if (pf < prefix) sb += v; \
          else if (pf > prefix) sa += v; \
          else { \
            unsigned int pos = atomicAdd(&lcnt, 1u); \
            if (pos < LCAP) buf[pos] = v; \
            else { \
              unsigned int g = atomicAdd(&ccount[bs * CPAD], 1u); \
              if (g < CAP) cd[g] = v; \
            } \
          } \
        }
      GCOL(a.x, 0x000000FFu)
      GCOL(a.y, 0x0000FF00u)
      GCOL(a.z, 0x00FF0000u)
      GCOL(a.w, 0xFF000000u)
      #undef GCOL
    }
  }
  __syncthreads();
  if (prefix >= 0) {
    unsigned int c = min(lcnt, (unsigned int)LCAP);
    if (t == 0 && c > 0) gbase = atomicAdd(&ccount[bs * CPAD], c);
    __syncthreads();
    if (c > 0) {
      float* cd = cand + (size_t)bs * CAP;
      unsigned int base = gbase;
      for (unsigned int i = t; i < c; i += 256) {
        unsigned int pos = base + i;
        if (pos < CAP) cd[pos] = buf[i];
      }
    }
  }
  float2 ts = breduce256x2(sb, sa, red);
  if (t == 0) {
    atomicAdd(&sbelow[bs], ts.x);
    atomicAdd(&sabove[bs], ts.y);
  }
}

// ---------- K5d: exact select among candidates (low 20 bits: 8/8/4) + scale ----------
__global__ __launch_bounds__(256) void gfinal_kernel(const float* __restrict__ cand,
                                                     const unsigned int* __restrict__ ccount,
                                                     const int* __restrict__ sel,
                                                     const float* __restrict__ sbelow,
                                                     const float* __restrict__ sabove,
                                                     float* __restrict__ gstats,
                                                     float* __restrict__ nvals) {
  const int bs = blockIdx.x;
  const int t = threadIdx.x;
  const int prefix = sel[bs * 4 + 0];
  const int r2 = sel[bs * 4 + 1];
  const int n = sel[bs * 4 + 2];
  const int nbelow = sel[bs * 4 + 3];
  __shared__ unsigned int hist[256];
  __shared__ float red[256];
  __shared__ int sh_bin, sh_r;
  __shared__ float sh_med;
  const float* cd = cand + (size_t)bs * CAP;
  int c = (int)min(ccount[bs * CPAD], (unsigned int)CAP);
  if (prefix < 0) {
    if (t == 0) {
      gstats[bs * 2 + 0] = 0.f;
      gstats[bs * 2 + 1] = 0.f;
      if ((bs & 1) == 0) nvals[bs >> 1] = 0.f;
    }
    return;
  }

  // pass 1: bits [19:12]
  hist[t] = 0;
  __syncthreads();
  for (int i = t; i < c; i += 256)
    atomicAdd(&hist[(fkey(cd[i]) >> 12) & 255u], 1u);
  __syncthreads();
  if (t == 0) {
    unsigned int rr = (unsigned int)r2, cum = 0;
    int bin = 0;
    for (; bin < 256; ++bin) {
      unsigned int h = hist[bin];
      if (cum + h > rr) break;
      cum += h;
    }
    sh_bin = bin;
    sh_r = (int)(rr - cum);
  }
  __syncthreads();
  const int bin1 = sh_bin;
  const int r3 = sh_r;

  // pass 2: bits [11:4]
  hist[t] = 0;
  __syncthreads();
  for (int i = t; i < c; i += 256) {
    unsigned int k = fkey(cd[i]);
    if (((k >> 12) & 255u) == (unsigned int)bin1)
      atomicAdd(&hist[(k >> 4) & 255u], 1u);
  }
  __syncthreads();
  if (t == 0) {
    unsigned int rr = (unsigned int)r3, cum = 0;
    int bin = 0;
    for (; bin < 256; ++bin) {
      unsigned int h = hist[bin];
      if (cum + h > rr) break;
      cum += h;
    }
    sh_bin = bin;
    sh_r = (int)(rr - cum);
  }
  __syncthreads();
  const int bin2 = sh_bin;
  const int r4 = sh_r;

  // pass 3: bits [3:0] (16 bins)
  if (t < 16) hist[t] = 0;
  __syncthreads();
  {
    const unsigned int want = (((unsigned int)bin1 << 8) | (unsigned int)bin2);
    for (int i = t; i < c; i += 256) {
      unsigned int k = fkey(cd[i]);
      if (((k >> 4) & 0xFFFFu) == want)
        atomicAdd(&hist[k & 15u], 1u);
    }
  }
  __syncthreads();
  if (t == 0) {
    unsigned int rr = (unsigned int)r4, cum = 0;
    int bin = 0;
    for (; bin < 16; ++bin) {
      unsigned int h = hist[bin];
      if (cum + h > rr) break;
      cum += h;
    }
    unsigned int key = ((unsigned int)prefix << 20) |
                       ((unsigned int)bin1 << 12) |
                       ((unsigned int)bin2 << 4) | (unsigned int)bin;
    sh_med = fkey_inv(key);
  }
  __syncthreads();
  const float med = sh_med;

  float ps = 0.f;
  for (int i = t; i < c; i += 256) ps += fabsf(cd[i] - med);
  float scand = breduce256(ps, red);
  if (t == 0) {
    float nb = (float)nbelow;
    float na = (float)(n - nbelow - c);
    float num = (nb * med - sbelow[bs]) + (sabove[bs] - na * med) + scand;
    gstats[bs * 2 + 0] = med;
    gstats[bs * 2 + 1] = num / fmaxf((float)n, 1.f);
    if ((bs & 1) == 0) nvals[bs >> 1] = (float)n;
  }
}

// ---------- K6a: global error partial sums (vectorized, both signals) ----------
__global__ __launch_bounds__(256) void gerr_kernel(const float* __restrict__ inp,
                                                   const float* __restrict__ tgt,
                                                   const unsigned char* __restrict__ mask,
                                                   const float* __restrict__ gstats,
                                                   float* __restrict__ gacc) {
  const int b = blockIdx.x / PSLICE;
  const int sl = blockIdx.x % PSLICE;
  __shared__ float red[256];
  const int t = threadIdx.x;
  const float med_i = gstats[(b * 2 + 0) * 2 + 0];
  const float sc_i = fmaxf(gstats[(b * 2 + 0) * 2 + 1], EPSV);
  const float med_t = gstats[(b * 2 + 1) * 2 + 0];
  const float sc_t = fmaxf(gstats[(b * 2 + 1) * 2 + 1], EPSV);
  const float ri = 1.f / sc_i, rt = 1.f / sc_t;
  const float4* xi4 = (const float4*)(inp + (size_t)b * HWN);
  const float4* xt4 = (const float4*)(tgt + (size_t)b * HWN);
  const unsigned int* m4 = (const unsigned int*)(mask + (size_t)b * HWN);
  const int per4 = (HWN / PSLICE) / 4;
  const int s0 = sl * per4;
  float part = 0.f;
  for (int i = s0 + t; i < s0 + per4; i += 256) {
    unsigned int mm = m4[i];
    if (!mm) continue;
    float4 a = xi4[i], c = xt4[i];
    if (mm & 0x000000FFu) part += fmaxf(fabsf((a.x - med_i) * ri - (c.x - med_t) * rt), EPSV);
    if (mm & 0x0000FF00u) part += fmaxf(fabsf((a.y - med_i) * ri - (c.y - med_t) * rt), EPSV);
    if (mm & 0x00FF0000u) part += fmaxf(fabsf((a.z - med_i) * ri - (c.z - med_t) * rt), EPSV);
    if (mm & 0xFF000000u) part += fmaxf(fabsf((a.w - med_i) * ri - (c.w - med_t) * rt), EPSV);
  }
  float tp = breduce256(part, red);
  if (t == 0) atomicAdd(&gacc[b], tp);
}

// ---------- K6b: combine ----------
__global__ __launch_bounds__(64) void final_kernel(const float* __restrict__ gacc,
                                                   const float* __restrict__ nvals,
                                                   const float* __restrict__ e_patch,
                                                   float* __restrict__ out) {
  const int b = threadIdx.x;
  if (b < BB) {
    float n = nvals[b];
    float eg = sqrtf(fmaxf(gacc[b] / fmaxf(n, 1.f), EPSV));
    out[b] = 0.5f * (e_patch[b] + eg);
  }
}

extern "C" void kernel_launch(void* const* d_in, const int* in_sizes, int n_in,
                              void* d_out, int out_size, void* d_ws, size_t ws_size,
                              hipStream_t stream) {
  const float* inp = (const float*)d_in[0];
  const float* tgt = (const float*)d_in[1];
  const unsigned char* mask = (const unsigned char*)d_in[2];   // jax bool -> 1 byte
  const float* image = (const float*)d_in[3];
  const unsigned char* vmask = (const unsigned char*)d_in[4];  // jax bool -> 1 byte
  float* out = (float*)d_out;

  float* ws = (float*)d_ws;
  float* re = ws;                                   // 48960
  int* coords = (int*)(ws + 48960);                 // 9792
  float* ep = ws + 48960 + 9792;                    // 4896
  float* val = ep + 4896;                           // 4896
  float* e_patch = val + 4896;                      // 32
  float* gstats = e_patch + 32;                     // 128
  float* nvals = gstats + 128;                      // 32
  int* sel12 = (int*)(nvals + 32);                  // 256 ints
  float* cand = (float*)(sel12 + 256);              // 64*CAP = 2,097,152 floats
  // zeroed region (one contiguous memset)
  unsigned int* ghist12 = (unsigned int*)(cand + (size_t)64 * CAP);  // 64*NB12
  unsigned int* ccount = ghist12 + (size_t)64 * NB12;                // 64*CPAD
  float* sbelow = (float*)(ccount + 64 * CPAD);                      // 64
  float* sabove = sbelow + 64;                                       // 64
  float* gacc = sabove + 64;                                         // 32
  size_t zero_bytes = ((size_t)64 * NB12 + 64 * CPAD + 64 + 64 + 32) * 4;
  hipMemsetAsync(ghist12, 0, zero_bytes, stream);

  // rpart (BB*TSLICE*OHW = 489,600 ints) aliases cand: topk finishes before
  // gcollect writes cand (stream-ordered), and coords is consumed by patch.
  int* rpart = (int*)cand;

  edge_resize_kernel<<<(BB * OHW * 4) / 256, 256, 0, stream>>>(image, vmask, re);
  topk_rank_kernel<<<BB * TSLICE, 256, 0, stream>>>(re, rpart);
  topk_write_kernel<<<BB, 256, 0, stream>>>(rpart, coords);
  patch_kernel<<<BB * KTOP, 64, 0, stream>>>(inp, tgt, mask, coords, ep, val);
  preduce_kernel<<<BB, 256, 0, stream>>>(ep, val, e_patch);
  gpass12_kernel<<<BB * PSLICE, 256, 0, stream>>>(inp, tgt, mask, ghist12);
  gsel12_kernel<<<BB * 2, 256, 0, stream>>>(ghist12, sel12);
  gcollect_kernel<<<BB * 2 * NSLICE, 256, 0, stream>>>(inp, tgt, mask, sel12, cand, ccount, sbelow, sabove);
  gfinal_kernel<<<BB * 2, 256, 0, stream>>>(cand, ccount, sel12, sbelow, sabove, gstats, nvals);
  gerr_kernel<<<BB * PSLICE, 256, 0, stream>>>(inp, tgt, mask, gstats, gacc);
  final_kernel<<<1, 64, 0, stream>>>(gacc, nvals, e_patch, out);
}